// Round 18
// baseline (105.458 us; speedup 1.0000x reference)
//
#include <hip/hip_runtime.h>
#include <math.h>

// TopK router: logits = x @ W^T + bias; top-2; softmax over the 2; scatter.
// x: [N=16384, H=4096] fp32, W: [E=64, H=4096] fp32, bias: [64] fp32.
// d_out: [N*64] final (fp32) then [N*2] selected_experts written as floats.
//
// Round 18 = round 17 (wave-private W tiles, no in-loop barriers, exact
// per-wave vmcnt 28/20/0) + ONE change: X loads are NON-TEMPORAL.
// Theory: five structures all plateau at 92-96us with every CU pipe idle
// because the CACHE HIERARCHY is the saturated resource: X (256MB, 32MB/
// XCD) thrashes the 4MB per-XCD L2, evicting the shared W planes, so W's
// 384MB of block re-reads (256 blocks x 1.5MB) fall to L3 alongside X ->
// ~500MB/92us ~= 5.4 TB/s ~= L3 ceiling for mixed scatter. X has ZERO
// reuse -> nt costs nothing, keeps X out of L2, W becomes L2-resident
// (384MB @ 34.5TB/s aggregate = 11us), L3/HBM serve only X.

constexpr int E_EXPERTS = 64;
constexpr int H_DIM = 4096;
constexpr int BLOCK = 512;   // 8 waves = 8 K-slices
constexpr int ROWS_B = 64;   // rows per block (shared by all waves)
constexpr int KSLICE = 512;  // k per wave
constexpr int NCH = 16;      // 32-k chunks per slice
constexpr int W_ELEMS = E_EXPERTS * H_DIM;
constexpr int TILE_SH = 8 * 512;      // 8 regions x 1KB = 4096 shorts
constexpr int WAVE_SH = 2 * TILE_SH;  // dbuf per wave (16 KB)

typedef __attribute__((ext_vector_type(8))) short short8;
typedef __attribute__((ext_vector_type(4))) float f32x4;

__device__ __forceinline__ float4 ld4(const float* p) {
  return *reinterpret_cast<const float4*>(p);
}
// Non-temporal 16B load: no-reuse X stream must not evict W from L2.
__device__ __forceinline__ float4 ld4nt(const float* p) {
  f32x4 v = __builtin_nontemporal_load(reinterpret_cast<const f32x4*>(p));
  return make_float4(v[0], v[1], v[2], v[3]);
}
__device__ __forceinline__ short8 lds8(const unsigned short* p) {
  return *reinterpret_cast<const short8*>(p);
}
__device__ __forceinline__ void gload16(const unsigned short* g,
                                        unsigned short* l) {
  __builtin_amdgcn_global_load_lds(
      (const __attribute__((address_space(1))) void*)g,
      (__attribute__((address_space(3))) void*)l, 16, 0, 0);
}

__device__ __forceinline__ unsigned short bf_rne(float x) {
  unsigned u = __builtin_bit_cast(unsigned, x);
  return (unsigned short)((u + 0x7fffu + ((u >> 16) & 1u)) >> 16);
}
__device__ __forceinline__ float bf2f(unsigned short b) {
  return __builtin_bit_cast(float, ((unsigned)b) << 16);
}
// x = h + m + l + err, |err| <= 2^-25 |x|. (h,m trunc; l RNE; residuals exact)
__device__ __forceinline__ void split3(float x, unsigned short& h,
                                       unsigned short& m, unsigned short& l) {
  unsigned short hb = (unsigned short)(__builtin_bit_cast(unsigned, x) >> 16);
  float r1 = x - bf2f(hb);
  unsigned short mb = (unsigned short)(__builtin_bit_cast(unsigned, r1) >> 16);
  float r2 = r1 - bf2f(mb);
  h = hb;
  m = mb;
  l = bf_rne(r2);
}
__device__ __forceinline__ void split3_8(float4 a, float4 b, short8& h,
                                         short8& m, short8& l) {
  unsigned short hh, mm, ll;
  split3(a.x, hh, mm, ll); h[0] = (short)hh; m[0] = (short)mm; l[0] = (short)ll;
  split3(a.y, hh, mm, ll); h[1] = (short)hh; m[1] = (short)mm; l[1] = (short)ll;
  split3(a.z, hh, mm, ll); h[2] = (short)hh; m[2] = (short)mm; l[2] = (short)ll;
  split3(a.w, hh, mm, ll); h[3] = (short)hh; m[3] = (short)mm; l[3] = (short)ll;
  split3(b.x, hh, mm, ll); h[4] = (short)hh; m[4] = (short)mm; l[4] = (short)ll;
  split3(b.y, hh, mm, ll); h[5] = (short)hh; m[5] = (short)mm; l[5] = (short)ll;
  split3(b.z, hh, mm, ll); h[6] = (short)hh; m[6] = (short)mm; l[6] = (short)ll;
  split3(b.w, hh, mm, ll); h[7] = (short)hh; m[7] = (short)mm; l[7] = (short)ll;
}

// Pre-kernel: split W into h/m/l bf16 planes (contiguous in d_ws).
__global__ __launch_bounds__(256) void split_w_kernel(
    const float* __restrict__ w, unsigned short* __restrict__ wh,
    unsigned short* __restrict__ wm, unsigned short* __restrict__ wl) {
  const int i = (blockIdx.x * 256 + threadIdx.x) * 4;
  float4 v = ld4(w + i);
  ushort4 h4, m4, l4;
  split3(v.x, h4.x, m4.x, l4.x);
  split3(v.y, h4.y, m4.y, l4.y);
  split3(v.z, h4.z, m4.z, l4.z);
  split3(v.w, h4.w, m4.w, l4.w);
  *reinterpret_cast<ushort4*>(wh + i) = h4;
  *reinterpret_cast<ushort4*>(wm + i) = m4;
  *reinterpret_cast<ushort4*>(wl + i) = l4;
}

__global__ __launch_bounds__(BLOCK, 2) void topk_router_mfma(
    const float* __restrict__ x, const unsigned short* __restrict__ wplanes,
    const float* __restrict__ bias, float* __restrict__ out_final,
    float* __restrict__ out_idx) {
  // 139264 B: stage area (8 waves x 16KB = 131072) + aliased fp32 partials.
  __shared__ f32x4 smem4[8704];
  unsigned short* sbase = reinterpret_cast<unsigned short*>(smem4);
  float* part = reinterpret_cast<float*>(smem4);

  const int tid = threadIdx.x;
  const int lane = tid & 63;
  const int kq = tid >> 6;  // wave = K slice (512 k)
  const int rowBase = blockIdx.x * ROWS_B;
  const int lr = lane & 15;
  const int kg = lane >> 4;

  unsigned short* lb = sbase + kq * WAVE_SH;  // wave-private dbuf

  // W bases. Region (ef, pl in {h=0,m=1}) index = ef*2+pl; lane ll holds
  // W_pl[ef*16 + (ll&15)][kq*512 + t*32 + (ll>>4)*8 ..+8) at slot ll*16B.
  const unsigned short* __restrict__ wb =
      wplanes + (size_t)lr * H_DIM + kq * KSLICE + kg * 8;
  const unsigned short* __restrict__ wlb = wb + (size_t)2 * W_ELEMS;  // l

#define STAGE(t, buf)                                                       \
  do {                                                                      \
    const size_t o_ = (size_t)(t) * 32;                                     \
    unsigned short* d_ = lb + (buf)*TILE_SH;                                \
    gload16(wb + o_, d_ + 0 * 512);                                         \
    gload16(wb + o_ + (size_t)W_ELEMS, d_ + 1 * 512);                       \
    gload16(wb + o_ + (size_t)16 * H_DIM, d_ + 2 * 512);                    \
    gload16(wb + o_ + (size_t)16 * H_DIM + (size_t)W_ELEMS, d_ + 3 * 512);  \
    gload16(wb + o_ + (size_t)32 * H_DIM, d_ + 4 * 512);                    \
    gload16(wb + o_ + (size_t)32 * H_DIM + (size_t)W_ELEMS, d_ + 5 * 512);  \
    gload16(wb + o_ + (size_t)48 * H_DIM, d_ + 6 * 512);                    \
    gload16(wb + o_ + (size_t)48 * H_DIM + (size_t)W_ELEMS, d_ + 7 * 512);  \
  } while (0)

  // X: the block's 64 rows = 4 A-frags per wave, this wave's 512-k slice.
  const float* __restrict__ xr0 =
      x + (size_t)(rowBase + lr) * H_DIM + kq * KSLICE + kg * 8;
  const float* __restrict__ xr1 = xr0 + (size_t)16 * H_DIM;
  const float* __restrict__ xr2 = xr0 + (size_t)32 * H_DIM;
  const float* __restrict__ xr3 = xr0 + (size_t)48 * H_DIM;

  float4 xA00, xA01, xA10, xA11, xA20, xA21, xA30, xA31;
  float4 xB00, xB01, xB10, xB11, xB20, xB21, xB30, xB31;
#define XLOADA(t)                                                         \
  do {                                                                    \
    xA00 = ld4nt(xr0 + (size_t)(t) * 32);                                 \
    xA01 = ld4nt(xr0 + (size_t)(t) * 32 + 4);                             \
    xA10 = ld4nt(xr1 + (size_t)(t) * 32);                                 \
    xA11 = ld4nt(xr1 + (size_t)(t) * 32 + 4);                             \
    xA20 = ld4nt(xr2 + (size_t)(t) * 32);                                 \
    xA21 = ld4nt(xr2 + (size_t)(t) * 32 + 4);                             \
    xA30 = ld4nt(xr3 + (size_t)(t) * 32);                                 \
    xA31 = ld4nt(xr3 + (size_t)(t) * 32 + 4);                             \
  } while (0)
#define XLOADB(t)                                                         \
  do {                                                                    \
    xB00 = ld4nt(xr0 + (size_t)(t) * 32);                                 \
    xB01 = ld4nt(xr0 + (size_t)(t) * 32 + 4);                             \
    xB10 = ld4nt(xr1 + (size_t)(t) * 32);                                 \
    xB11 = ld4nt(xr1 + (size_t)(t) * 32 + 4);                             \
    xB20 = ld4nt(xr2 + (size_t)(t) * 32);                                 \
    xB21 = ld4nt(xr2 + (size_t)(t) * 32 + 4);                             \
    xB30 = ld4nt(xr3 + (size_t)(t) * 32);                                 \
    xB31 = ld4nt(xr3 + (size_t)(t) * 32 + 4);                             \
  } while (0)

  f32x4 c00 = {0.f, 0.f, 0.f, 0.f}, c01 = c00, c02 = c00, c03 = c00,
        c10 = c00, c11 = c00, c12 = c00, c13 = c00, c20 = c00, c21 = c00,
        c22 = c00, c23 = c00, c30 = c00, c31 = c00, c32 = c00, c33 = c00;

#define MM(d, a, b) d = __builtin_amdgcn_mfma_f32_16x16x32_bf16(a, b, d, 0, 0, 0)
#define PROD6(d, Ah, Am, Al, Bh, Bm, Bl)                      \
  MM(d, Ah, Bh); MM(d, Ah, Bm); MM(d, Am, Bh); MM(d, Am, Bm); \
  MM(d, Ah, Bl); MM(d, Al, Bh)

  // Prologue: stage chunk 0 -> buf0; X chunks 0,1 in flight. No waits.
  STAGE(0, 0);
  XLOADA(0);
  XLOADB(1);

  // Per-wave chunk body. vmcnt counts (sched_barrier-fenced issue order):
  // c==0: newer than STAGE(0) = XA(0)8 + XB(1)8 + STAGE(1)8 + WL(0)4 = 28.
  // 1<=c<=14: newer than STAGE(c) = X(c+1)8 + STAGE(c+1)8 + WL(c)4 = 20.
  // c==15: drain (no stage/X issued after) = 0.
#define BODY(c, X00, X01, X10, X11, X20, X21, X30, X31, XLOADM)              \
  do {                                                                       \
    if ((c) + 1 < NCH) STAGE((c) + 1, ((c) + 1) & 1);                        \
    const size_t wo_ = (size_t)(c) * 32;                                     \
    short8 bl0 = lds8(wlb + wo_);                                            \
    short8 bl1 = lds8(wlb + wo_ + (size_t)16 * H_DIM);                       \
    short8 bl2 = lds8(wlb + wo_ + (size_t)32 * H_DIM);                       \
    short8 bl3 = lds8(wlb + wo_ + (size_t)48 * H_DIM);                       \
    __builtin_amdgcn_sched_barrier(0);                                       \
    if ((c) == 0) {                                                          \
      asm volatile("s_waitcnt vmcnt(28)" ::: "memory");                      \
    } else if ((c) <= 14) {                                                  \
      asm volatile("s_waitcnt vmcnt(20)" ::: "memory");                      \
    } else {                                                                 \
      asm volatile("s_waitcnt vmcnt(0)" ::: "memory");                       \
    }                                                                        \
    __builtin_amdgcn_sched_barrier(0);                                       \
    const unsigned short* tb_ = lb + ((c)&1) * TILE_SH;                      \
    short8 b0h = lds8(tb_ + 0 * 512 + lane * 8);                             \
    short8 b0m = lds8(tb_ + 1 * 512 + lane * 8);                             \
    short8 b1h = lds8(tb_ + 2 * 512 + lane * 8);                             \
    short8 b1m = lds8(tb_ + 3 * 512 + lane * 8);                             \
    short8 b2h = lds8(tb_ + 4 * 512 + lane * 8);                             \
    short8 b2m = lds8(tb_ + 5 * 512 + lane * 8);                             \
    short8 b3h = lds8(tb_ + 6 * 512 + lane * 8);                             \
    short8 b3m = lds8(tb_ + 7 * 512 + lane * 8);                             \
    short8 a0h, a0m, a0l, a1h, a1m, a1l, a2h, a2m, a2l, a3h, a3m, a3l;       \
    split3_8(X00, X01, a0h, a0m, a0l);                                       \
    split3_8(X10, X11, a1h, a1m, a1l);                                       \
    split3_8(X20, X21, a2h, a2m, a2l);                                       \
    split3_8(X30, X31, a3h, a3m, a3l);                                       \
    if ((c) + 2 < NCH) XLOADM((c) + 2); /* after splits: WAR-safe */         \
    PROD6(c00, a0h, a0m, a0l, b0h, b0m, bl0);                                \
    PROD6(c01, a0h, a0m, a0l, b1h, b1m, bl1);                                \
    PROD6(c02, a0h, a0m, a0l, b2h, b2m, bl2);                                \
    PROD6(c03, a0h, a0m, a0l, b3h, b3m, bl3);                                \
    PROD6(c10, a1h, a1m, a1l, b0h, b0m, bl0);                                \
    PROD6(c11, a1h, a1m, a1l, b1h, b1m, bl1);                                \
    PROD6(c12, a1h, a1m, a1l, b2h, b2m, bl2);                                \
    PROD6(c13, a1h, a1m, a1l, b3h, b3m, bl3);                                \
    PROD6(c20, a2h, a2m, a2l, b0h, b0m, bl0);                                \
    PROD6(c21, a2h, a2m, a2l, b1h, b1m, bl1);                                \
    PROD6(c22, a2h, a2m, a2l, b2h, b2m, bl2);                                \
    PROD6(c23, a2h, a2m, a2l, b3h, b3m, bl3);                                \
    PROD6(c30, a3h, a3m, a3l, b0h, b0m, bl0);                                \
    PROD6(c31, a3h, a3m, a3l, b1h, b1m, bl1);                                \
    PROD6(c32, a3h, a3m, a3l, b2h, b2m, bl2);                                \
    PROD6(c33, a3h, a3m, a3l, b3h, b3m, bl3);                                \
  } while (0)

  for (int c = 0; c < NCH; c += 2) {
    BODY(c, xA00, xA01, xA10, xA11, xA20, xA21, xA30, xA31, XLOADA);
    BODY(c + 1, xB00, xB01, xB10, xB11, xB20, xB21, xB30, xB31, XLOADB);
  }

  // All waves must finish READING their stage LDS before part overwrites it.
  __syncthreads();

  // Partials: part[kq][row][e], row pad 68 floats (139264 B total).
  const int pr = kg * 4;
#define PST(A, af, g)                                                      \
  part[(size_t)(kq * 64 + (af)*16 + pr + 0) * 68 + (g)*16 + lr] = A[0];    \
  part[(size_t)(kq * 64 + (af)*16 + pr + 1) * 68 + (g)*16 + lr] = A[1];    \
  part[(size_t)(kq * 64 + (af)*16 + pr + 2) * 68 + (g)*16 + lr] = A[2];    \
  part[(size_t)(kq * 64 + (af)*16 + pr + 3) * 68 + (g)*16 + lr] = A[3];
  PST(c00, 0, 0) PST(c01, 0, 1) PST(c02, 0, 2) PST(c03, 0, 3)
  PST(c10, 1, 0) PST(c11, 1, 1) PST(c12, 1, 2) PST(c13, 1, 3)
  PST(c20, 2, 0) PST(c21, 2, 1) PST(c22, 2, 2) PST(c23, 2, 3)
  PST(c30, 3, 0) PST(c31, 3, 1) PST(c32, 3, 2) PST(c33, 3, 3)
  __syncthreads();

  // Epilogue: 8 threads/row, 8 experts each; ordered 8-way kq tree,
  // stable top-2 scan, shfl_xor merge (d=1,2,4), softmax, scatter.
  const int r = tid >> 3;
  const int eb = (tid & 7) * 8;
  const int n = rowBase + r;

  float v8[8];
#pragma unroll
  for (int j = 0; j < 8; ++j) {
    int e = eb + j;
    float s01 = part[(size_t)(0 * 64 + r) * 68 + e] +
                part[(size_t)(1 * 64 + r) * 68 + e];
    float s23 = part[(size_t)(2 * 64 + r) * 68 + e] +
                part[(size_t)(3 * 64 + r) * 68 + e];
    float s45 = part[(size_t)(4 * 64 + r) * 68 + e] +
                part[(size_t)(5 * 64 + r) * 68 + e];
    float s67 = part[(size_t)(6 * 64 + r) * 68 + e] +
                part[(size_t)(7 * 64 + r) * 68 + e];
    v8[j] = ((s01 + s23) + (s45 + s67)) + bias[e];
  }

  float av = -INFINITY, bv = -INFINITY;
  int ai = E_EXPERTS, bi = E_EXPERTS;
#pragma unroll
  for (int j = 0; j < 8; ++j) {
    int e = eb + j;
    float v = v8[j];
    bool beats_a = (v > av) || (v == av && e < ai);
    bool beats_b = (v > bv) || (v == bv && e < bi);
    if (beats_a) {
      bv = av; bi = ai; av = v; ai = e;
    } else if (beats_b) {
      bv = v; bi = e;
    }
  }
#pragma unroll
  for (int d = 1; d < 8; d <<= 1) {
    float av2 = __shfl_xor(av, d);
    float bv2 = __shfl_xor(bv, d);
    int ai2 = __shfl_xor(ai, d);
    int bi2 = __shfl_xor(bi, d);
    bool afirst = (av > av2) || (av == av2 && ai < ai2);
    float na, nb;
    int nai, nbi;
    if (afirst) {
      na = av; nai = ai;
      bool t = (bv > av2) || (bv == av2 && bi < ai2);
      nb = t ? bv : av2;
      nbi = t ? bi : ai2;
    } else {
      na = av2; nai = ai2;
      bool t = (av > bv2) || (av == bv2 && ai < bi2);
      nb = t ? av : bv2;
      nbi = t ? ai : bi2;
    }
    av = na; ai = nai; bv = nb; bi = nbi;
  }

  float e1 = expf(bv - av);
  float denom = 1.0f + e1;
  float p0 = 1.0f / denom;
  float p1 = e1 / denom;

#pragma unroll
  for (int i = 0; i < 2; ++i) {
    float4 o4;
    float* po = &o4.x;
#pragma unroll
    for (int j = 0; j < 4; ++j) {
      int e = eb + i * 4 + j;
      po[j] = (e == ai) ? p0 : (e == bi) ? p1 : 0.0f;
    }
    *reinterpret_cast<float4*>(&out_final[(size_t)n * E_EXPERTS + eb + i * 4]) =
        o4;
  }
  if ((tid & 7) == 0) {
    out_idx[(size_t)n * 2 + 0] = (float)ai;
    out_idx[(size_t)n * 2 + 1] = (float)bi;
  }
}

extern "C" void kernel_launch(void* const* d_in, const int* in_sizes, int n_in,
                              void* d_out, int out_size, void* d_ws,
                              size_t ws_size, hipStream_t stream) {
  const float* x = (const float*)d_in[0];
  const float* w = (const float*)d_in[1];
  const float* bias = (const float*)d_in[2];
  const int N = in_sizes[0] / H_DIM;  // 16384
  float* out_final = (float*)d_out;
  float* out_idx = out_final + (size_t)N * E_EXPERTS;

  unsigned short* wh = (unsigned short*)d_ws;  // h | m | l contiguous
  unsigned short* wm = wh + W_ELEMS;
  unsigned short* wl = wm + W_ELEMS;

  split_w_kernel<<<W_ELEMS / (256 * 4), 256, 0, stream>>>(w, wh, wm, wl);
  topk_router_mfma<<<N / ROWS_B, BLOCK, 0, stream>>>(x, wh, bias, out_final,
                                                     out_idx);
}